// Round 1
// baseline (858.888 us; speedup 1.0000x reference)
//
#include <hip/hip_runtime.h>

#define NB 8
#define NC 512
#define NO 64
#define NH 64
#define NW 64
#define NHW 4096

// K1: fused QKV projection. Per batch: [640x512] @ [512x4096].
// Rows 0..63 -> q (Wq), 64..127 -> k (Wk), 128..639 -> v (Wv).
__global__ __launch_bounds__(256) void qkv_gemm(
    const float* __restrict__ x,
    const float* __restrict__ Wq, const float* __restrict__ bq,
    const float* __restrict__ Wk, const float* __restrict__ bk,
    const float* __restrict__ Wv, const float* __restrict__ bv,
    float* __restrict__ q, float* __restrict__ k, float* __restrict__ v)
{
    __shared__ float Ws[16][68];   // [kk][oo], pad 68 keeps b128 align + 2-way banks
    __shared__ float Xs[16][64];   // [kk][hw]
    const int t = threadIdx.x;
    const int tx = t & 15, ty = t >> 4;
    const int b = blockIdx.z;
    const int o0 = blockIdx.y * 64;
    const int hw0 = blockIdx.x * 64;
    float acc[4][4] = {};
    for (int c0 = 0; c0 < NC; c0 += 16) {
        {
            const int colw = t & 63;
            const int rbase = t >> 6;
            #pragma unroll
            for (int s = 0; s < 4; ++s) {
                int r = rbase + 4*s;
                Xs[r][colw] = x[(size_t)(b*NC + c0 + r)*NHW + hw0 + colw];
            }
            const int kk = t & 15;
            const int obase = t >> 4;
            #pragma unroll
            for (int s = 0; s < 4; ++s) {
                int oo = obase + 16*s;
                int ro = o0 + oo;
                const float* wr = (ro < 64)  ? (Wq + ro*NC)
                                : (ro < 128) ? (Wk + (ro-64)*NC)
                                :              (Wv + (ro-128)*NC);
                Ws[kk][oo] = wr[c0 + kk];
            }
        }
        __syncthreads();
        #pragma unroll
        for (int kk = 0; kk < 16; ++kk) {
            float av[4], bv4[4];
            *(float4*)av  = *(const float4*)&Ws[kk][ty*4];
            *(float4*)bv4 = *(const float4*)&Xs[kk][tx*4];
            #pragma unroll
            for (int i = 0; i < 4; ++i)
                #pragma unroll
                for (int j = 0; j < 4; ++j)
                    acc[i][j] += av[i]*bv4[j];
        }
        __syncthreads();
    }
    #pragma unroll
    for (int i = 0; i < 4; ++i) {
        int ro = o0 + ty*4 + i;
        float bias; float* dst;
        if (ro < 64)       { bias = bq[ro];      dst = q + (size_t)(b*NO + ro)*NHW; }
        else if (ro < 128) { bias = bk[ro-64];   dst = k + (size_t)(b*NO + (ro-64))*NHW; }
        else               { bias = bv[ro-128];  dst = v + (size_t)(b*NC + (ro-128))*NHW; }
        float4 r4;
        r4.x = acc[i][0] + bias;
        r4.y = acc[i][1] + bias;
        r4.z = acc[i][2] + bias;
        r4.w = acc[i][3] + bias;
        *(float4*)&dst[hw0 + tx*4] = r4;
    }
}

// K2: scores + softmax, block per (b, h). Writes transposed attention maps:
//   aH2[b][h][i][w], aW2[b][h][j][w]
__global__ __launch_bounds__(256) void scores_softmax(
    const float* __restrict__ q, const float* __restrict__ k,
    float* __restrict__ aH2, float* __restrict__ aW2)
{
    __shared__ float qs[64][64];   // [o][w]  q row at h=hb
    __shared__ float ksr[64][64];  // [o][j]  k row at h=hb
    __shared__ float sH[64][65];   // [w][i]
    __shared__ float sW[64][65];   // [w][j]
    __shared__ float red[8][64];
    const int t = threadIdx.x;
    const int w = t & 63, p = t >> 6;
    const int hb = blockIdx.x, b = blockIdx.y;
    #pragma unroll
    for (int s = 0; s < 16; ++s) {
        int idx = t + 256*s;
        int o = idx >> 6, ww = idx & 63;
        size_t g = (size_t)(b*NO + o)*NHW + hb*NW + ww;
        qs[o][ww]  = q[g];
        ksr[o][ww] = k[g];
    }
    __syncthreads();
    const int ib = p * 16;
    { // column scores: sH[w][i] = sum_o qs[o][w] * k[b][o][i][w]
        float acc[16];
        #pragma unroll
        for (int ii = 0; ii < 16; ++ii) acc[ii] = 0.f;
        for (int o = 0; o < 64; ++o) {
            float qv = qs[o][w];
            const float* kp = k + (size_t)(b*NO + o)*NHW + ib*NW + w;
            #pragma unroll
            for (int ii = 0; ii < 16; ++ii) acc[ii] += qv * kp[ii*NW];
        }
        #pragma unroll
        for (int ii = 0; ii < 16; ++ii) sH[w][ib+ii] = acc[ii];
    }
    { // row scores: sW[w][j] = sum_o qs[o][w] * ksr[o][j]
        float acc[16];
        #pragma unroll
        for (int jj = 0; jj < 16; ++jj) acc[jj] = 0.f;
        for (int o = 0; o < 64; ++o) {
            float qv = qs[o][w];
            #pragma unroll
            for (int jj = 0; jj < 16; ++jj) acc[jj] += qv * ksr[o][ib+jj];
        }
        #pragma unroll
        for (int jj = 0; jj < 16; ++jj) sW[w][ib+jj] = acc[jj];
    }
    __syncthreads();
    if (t < 64) sH[t][hb] = -1e30f;   // diag mask i == h
    __syncthreads();
    // softmax over 128 logits per w; thread (w,p) owns 32 of them
    float m = -1e30f;
    #pragma unroll
    for (int z = 0; z < 32; ++z) {
        float val = (p < 2) ? sH[w][p*32+z] : sW[w][(p-2)*32+z];
        m = fmaxf(m, val);
    }
    red[p][w] = m;
    __syncthreads();
    float M = fmaxf(fmaxf(red[0][w], red[1][w]), fmaxf(red[2][w], red[3][w]));
    float ssum = 0.f;
    #pragma unroll
    for (int z = 0; z < 32; ++z) {
        float* slot = (p < 2) ? &sH[w][p*32+z] : &sW[w][(p-2)*32+z];
        float e = __expf(*slot - M);
        ssum += e;
        *slot = e;
    }
    red[4+p][w] = ssum;
    __syncthreads();
    float S = red[4][w] + red[5][w] + red[6][w] + red[7][w];
    float rinv = 1.f / S;
    const size_t obase = (size_t)(b*NO + hb)*NHW;
    #pragma unroll
    for (int z = 0; z < 32; ++z) {
        if (p < 2) {
            int i = p*32 + z;
            aH2[obase + i*NW + w] = sH[w][i] * rinv;
        } else {
            int j = (p-2)*32 + z;
            aW2[obase + j*NW + w] = sW[w][j] * rinv;
        }
    }
}

// K3: column pass, block per (b, w): out[c][h] = sum_i v[b][c][i][w] * aH[b,h,w,i]
__global__ __launch_bounds__(256) void col_pass(
    const float* __restrict__ v, const float* __restrict__ aH2,
    float* __restrict__ out)
{
    __shared__ float vcs[512*68];  // [c][i] stride 68
    __shared__ float AlT[64*68];   // [i][h] stride 68
    const int t = threadIdx.x;
    const int w = blockIdx.x, b = blockIdx.y;
    #pragma unroll 2
    for (int s = 0; s < 16; ++s) {
        int idx = t + 256*s;
        int h = idx >> 6, i = idx & 63;
        AlT[i*68 + h] = aH2[(size_t)(b*NO + h)*NHW + i*NW + w];
    }
    #pragma unroll 4
    for (int s = 0; s < 128; ++s) {
        int idx = t + 256*s;
        int c = idx >> 6, i = idx & 63;
        vcs[c*68 + i] = v[(size_t)(b*NC + c)*NHW + i*NW + w];
    }
    __syncthreads();
    const int h4 = t & 15, cg = t >> 4;
    for (int cb = 0; cb < 8; ++cb) {
        const int c = (cb*16 + cg)*4;
        float acc[4][4] = {};
        #pragma unroll
        for (int i0 = 0; i0 < 64; i0 += 4) {
            float aa[4][4], vv[4][4];
            #pragma unroll
            for (int di = 0; di < 4; ++di)
                *(float4*)aa[di] = *(const float4*)&AlT[(i0+di)*68 + h4*4];
            #pragma unroll
            for (int r = 0; r < 4; ++r)
                *(float4*)vv[r] = *(const float4*)&vcs[(c+r)*68 + i0];
            #pragma unroll
            for (int r = 0; r < 4; ++r)
                #pragma unroll
                for (int di = 0; di < 4; ++di)
                    #pragma unroll
                    for (int hh = 0; hh < 4; ++hh)
                        acc[r][hh] += vv[r][di] * aa[di][hh];
        }
        #pragma unroll
        for (int r = 0; r < 4; ++r)
            #pragma unroll
            for (int hh = 0; hh < 4; ++hh)
                out[(size_t)((b*NC + c + r)*NH + h4*4 + hh)*NW + w] = acc[r][hh];
    }
}

// K4: row pass + residual, block per (b, h):
//   out = gamma*(colsum + sum_j v[b][c][h][j]*aW[b,h,w,j]) + x
__global__ __launch_bounds__(256) void row_pass(
    const float* __restrict__ v, const float* __restrict__ aW2,
    const float* __restrict__ x, const float* __restrict__ gamma,
    float* __restrict__ out)
{
    __shared__ float vrs[512*68];  // [c][j]
    __shared__ float AwT[64*68];   // [j][w]
    const int t = threadIdx.x;
    const int hb = blockIdx.x, b = blockIdx.y;
    #pragma unroll 2
    for (int s = 0; s < 16; ++s) {
        int idx = t + 256*s;
        int j = idx >> 6, ww = idx & 63;
        AwT[j*68 + ww] = aW2[(size_t)(b*NO + hb)*NHW + j*NW + ww];
    }
    #pragma unroll 4
    for (int s = 0; s < 128; ++s) {
        int idx = t + 256*s;
        int c = idx >> 6, j = idx & 63;
        vrs[c*68 + j] = v[(size_t)(b*NC + c)*NHW + hb*NW + j];
    }
    __syncthreads();
    const float g = gamma[0];
    const int w4 = t & 15, cg = t >> 4;
    for (int cb = 0; cb < 8; ++cb) {
        const int c = (cb*16 + cg)*4;
        float acc[4][4] = {};
        #pragma unroll
        for (int j0 = 0; j0 < 64; j0 += 4) {
            float aa[4][4], vv[4][4];
            #pragma unroll
            for (int dj = 0; dj < 4; ++dj)
                *(float4*)aa[dj] = *(const float4*)&AwT[(j0+dj)*68 + w4*4];
            #pragma unroll
            for (int r = 0; r < 4; ++r)
                *(float4*)vv[r] = *(const float4*)&vrs[(c+r)*68 + j0];
            #pragma unroll
            for (int r = 0; r < 4; ++r)
                #pragma unroll
                for (int dj = 0; dj < 4; ++dj)
                    #pragma unroll
                    for (int ww = 0; ww < 4; ++ww)
                        acc[r][ww] += vv[r][dj] * aa[dj][ww];
        }
        #pragma unroll
        for (int r = 0; r < 4; ++r) {
            size_t base = (size_t)((b*NC + c + r)*NH + hb)*NW + w4*4;
            float4 cv = *(const float4*)&out[base];
            float4 xv = *(const float4*)&x[base];
            float4 res;
            res.x = g*(cv.x + acc[r][0]) + xv.x;
            res.y = g*(cv.y + acc[r][1]) + xv.y;
            res.z = g*(cv.z + acc[r][2]) + xv.z;
            res.w = g*(cv.w + acc[r][3]) + xv.w;
            *(float4*)&out[base] = res;
        }
    }
}

extern "C" void kernel_launch(void* const* d_in, const int* in_sizes, int n_in,
                              void* d_out, int out_size, void* d_ws, size_t ws_size,
                              hipStream_t stream) {
    (void)in_sizes; (void)n_in; (void)out_size; (void)ws_size;
    const float* x     = (const float*)d_in[0];
    const float* Wq    = (const float*)d_in[1];
    const float* bq    = (const float*)d_in[2];
    const float* Wk    = (const float*)d_in[3];
    const float* bk    = (const float*)d_in[4];
    const float* Wv    = (const float*)d_in[5];
    const float* bv    = (const float*)d_in[6];
    const float* gamma = (const float*)d_in[7];
    float* out = (float*)d_out;

    float* q   = (float*)d_ws;            // 2,097,152 f32
    float* k   = q   + 2097152;           // 2,097,152
    float* v   = k   + 2097152;           // 16,777,216
    float* aH2 = v   + 16777216;          // 2,097,152
    float* aW2 = aH2 + 2097152;           // 2,097,152  (total ~100.7 MB)

    qkv_gemm<<<dim3(NHW/64, 640/64, NB), 256, 0, stream>>>(x, Wq, bq, Wk, bk, Wv, bv, q, k, v);
    scores_softmax<<<dim3(NH, NB), 256, 0, stream>>>(q, k, aH2, aW2);
    col_pass<<<dim3(NW, NB), 256, 0, stream>>>(v, aH2, out);
    row_pass<<<dim3(NH, NB), 256, 0, stream>>>(v, aW2, x, gamma, out);
}

// Round 2
// 622.769 us; speedup vs baseline: 1.3791x; 1.3791x over previous
//
#include <hip/hip_runtime.h>
#include <hip/hip_bf16.h>

#define NB 8
#define NC 512
#define NO 64
#define NH 64
#define NW 64
#define NHW 4096

typedef __attribute__((ext_vector_type(8))) short bf16x8;
typedef __attribute__((ext_vector_type(4))) float f32x4;

__device__ __forceinline__ void gload16(const void* g, void* l) {
    __builtin_amdgcn_global_load_lds(
        (const __attribute__((address_space(1))) void*)g,
        (__attribute__((address_space(3))) void*)l, 16, 0, 0);
}

// K0a: pack Wq|Wk|Wv -> Wbf[640][512] bf16, biases -> bias_all[640] f32
__global__ __launch_bounds__(256) void pack_w(
    const float* __restrict__ Wq, const float* __restrict__ bq,
    const float* __restrict__ Wk, const float* __restrict__ bk,
    const float* __restrict__ Wv, const float* __restrict__ bv,
    __hip_bfloat16* __restrict__ Wbf, float* __restrict__ bias_all)
{
    const int row = blockIdx.x;
    const int t = threadIdx.x;
    const float* src; float bias;
    if (row < 64)       { src = Wq + row*NC;        bias = bq[row]; }
    else if (row < 128) { src = Wk + (row-64)*NC;   bias = bk[row-64]; }
    else                { src = Wv + (row-128)*NC;  bias = bv[row-128]; }
    for (int i = t; i < NC; i += 256)
        Wbf[(size_t)row*NC + i] = __float2bfloat16(src[i]);
    if (t == 0) bias_all[row] = bias;
}

// K0b: x[b][c][hw] f32 -> xt[b][hw][c] bf16 (LDS tile transpose)
__global__ __launch_bounds__(256) void transpose_x(
    const float* __restrict__ x, __hip_bfloat16* __restrict__ xt)
{
    __shared__ float tile[64][65];
    const int c0  = blockIdx.x * 64;
    const int hw0 = blockIdx.y * 64;
    const int b   = blockIdx.z;
    const int t = threadIdx.x;
    const int col = t & 63, r4 = t >> 6;
    #pragma unroll
    for (int s = 0; s < 16; ++s) {
        int cr = s*4 + r4;
        tile[cr][col] = x[((size_t)b*NC + c0 + cr)*NHW + hw0 + col];
    }
    __syncthreads();
    #pragma unroll
    for (int s = 0; s < 16; ++s) {
        int wr = s*4 + r4;
        xt[((size_t)b*NHW + hw0 + wr)*NC + c0 + col] = __float2bfloat16(tile[col][wr]);
    }
}

// K1: MFMA QKV projection. Per batch: [640x512] @ [512x4096]^T-staged.
// A = Wbf [o][c], B = xt[b][hw][c] (both k-contiguous). 128x128 tile, BK=64,
// 4 waves (2x2), each wave 64x64 via 4x4 frags of 16x16x32.
__global__ __launch_bounds__(256) void qkv_mfma(
    const __hip_bfloat16* __restrict__ xt, const __hip_bfloat16* __restrict__ Wbf,
    const float* __restrict__ bias_all,
    __hip_bfloat16* __restrict__ qb, __hip_bfloat16* __restrict__ kb,
    __hip_bfloat16* __restrict__ vb)
{
    __shared__ __align__(16) char As[16384];   // [row 128][k 64] bf16, src-preswizzled
    __shared__ __align__(16) char Bs[16384];   // [col 128][k 64] bf16
    const int t = threadIdx.x;
    const int lane = t & 63;
    const int wv = t >> 6;
    const int wm = wv >> 1, wn = wv & 1;
    const int fr = lane & 15, fg = lane >> 4;
    const int hw0 = blockIdx.x * 128;
    const int o0  = blockIdx.y * 128;
    const int b   = blockIdx.z;
    const __hip_bfloat16* xtb = xt + (size_t)b * NHW * NC;

    f32x4 acc[4][4] = {};

    for (int ks = 0; ks < 8; ++ks) {
        const int k0 = ks * 64;
        #pragma unroll
        for (int s = 0; s < 4; ++s) {
            int linear = s*256 + t;
            int row = linear >> 3, g = linear & 7;
            int gk = (g ^ (row & 7)) * 8;          // source pre-swizzle (XOR involution)
            gload16(Wbf + (size_t)(o0 + row)*NC + k0 + gk, As + linear*16);
            gload16(xtb + (size_t)(hw0 + row)*NC + k0 + gk, Bs + linear*16);
        }
        __syncthreads();   // compiler drains vmcnt(0) before s_barrier
        #pragma unroll
        for (int kk = 0; kk < 2; ++kk) {
            const int gl = kk*4 + fg;
            bf16x8 af[4], bfr[4];
            #pragma unroll
            for (int mf = 0; mf < 4; ++mf) {
                int r = wm*64 + mf*16 + fr;
                af[mf] = *(const bf16x8*)(As + r*128 + ((gl ^ (r & 7)) << 4));
            }
            #pragma unroll
            for (int nf = 0; nf < 4; ++nf) {
                int c = wn*64 + nf*16 + fr;
                bfr[nf] = *(const bf16x8*)(Bs + c*128 + ((gl ^ (c & 7)) << 4));
            }
            #pragma unroll
            for (int mf = 0; mf < 4; ++mf)
                #pragma unroll
                for (int nf = 0; nf < 4; ++nf)
                    acc[mf][nf] = __builtin_amdgcn_mfma_f32_16x16x32_bf16(
                        af[mf], bfr[nf], acc[mf][nf], 0, 0, 0);
        }
        __syncthreads();
    }

    // epilogue: C/D layout col=lane&15, row=(lane>>4)*4+reg (verified mapping)
    #pragma unroll
    for (int mf = 0; mf < 4; ++mf) {
        #pragma unroll
        for (int reg = 0; reg < 4; ++reg) {
            int o = o0 + wm*64 + mf*16 + (lane >> 4)*4 + reg;
            float bias = bias_all[o];
            __hip_bfloat16* dst; size_t rowbase;
            if (o < 64)       { dst = qb; rowbase = ((size_t)b*NO + o)*NHW; }
            else if (o < 128) { dst = kb; rowbase = ((size_t)b*NO + (o-64))*NHW; }
            else              { dst = vb; rowbase = ((size_t)b*NC + (o-128))*NHW; }
            #pragma unroll
            for (int nf = 0; nf < 4; ++nf) {
                int hw = hw0 + wn*64 + nf*16 + (lane & 15);
                dst[rowbase + hw] = __float2bfloat16(acc[mf][nf][reg] + bias);
            }
        }
    }
}

// K2: scores + softmax, block per (b, h). Writes transposed attention maps:
//   aH2[b][h][i][w], aW2[b][h][j][w]
__global__ __launch_bounds__(256) void scores_softmax(
    const __hip_bfloat16* __restrict__ q, const __hip_bfloat16* __restrict__ k,
    float* __restrict__ aH2, float* __restrict__ aW2)
{
    __shared__ float qs[64][64];   // [o][w]  q row at h=hb
    __shared__ float ksr[64][64];  // [o][j]  k row at h=hb
    __shared__ float sH[64][65];   // [w][i]
    __shared__ float sW[64][65];   // [w][j]
    __shared__ float red[8][64];
    const int t = threadIdx.x;
    const int w = t & 63, p = t >> 6;
    const int hb = blockIdx.x, b = blockIdx.y;
    #pragma unroll
    for (int s = 0; s < 16; ++s) {
        int idx = t + 256*s;
        int o = idx >> 6, ww = idx & 63;
        size_t g = (size_t)(b*NO + o)*NHW + hb*NW + ww;
        qs[o][ww]  = __bfloat162float(q[g]);
        ksr[o][ww] = __bfloat162float(k[g]);
    }
    __syncthreads();
    const int ib = p * 16;
    { // column scores: sH[w][i] = sum_o qs[o][w] * k[b][o][i][w]
        float acc[16];
        #pragma unroll
        for (int ii = 0; ii < 16; ++ii) acc[ii] = 0.f;
        for (int o = 0; o < 64; ++o) {
            float qv = qs[o][w];
            const __hip_bfloat16* kp = k + (size_t)(b*NO + o)*NHW + ib*NW + w;
            #pragma unroll
            for (int ii = 0; ii < 16; ++ii) acc[ii] += qv * __bfloat162float(kp[ii*NW]);
        }
        #pragma unroll
        for (int ii = 0; ii < 16; ++ii) sH[w][ib+ii] = acc[ii];
    }
    { // row scores: sW[w][j] = sum_o qs[o][w] * ksr[o][j]
        float acc[16];
        #pragma unroll
        for (int jj = 0; jj < 16; ++jj) acc[jj] = 0.f;
        for (int o = 0; o < 64; ++o) {
            float qv = qs[o][w];
            #pragma unroll
            for (int jj = 0; jj < 16; ++jj) acc[jj] += qv * ksr[o][ib+jj];
        }
        #pragma unroll
        for (int jj = 0; jj < 16; ++jj) sW[w][ib+jj] = acc[jj];
    }
    __syncthreads();
    if (t < 64) sH[t][hb] = -1e30f;   // diag mask i == h
    __syncthreads();
    float m = -1e30f;
    #pragma unroll
    for (int z = 0; z < 32; ++z) {
        float val = (p < 2) ? sH[w][p*32+z] : sW[w][(p-2)*32+z];
        m = fmaxf(m, val);
    }
    red[p][w] = m;
    __syncthreads();
    float M = fmaxf(fmaxf(red[0][w], red[1][w]), fmaxf(red[2][w], red[3][w]));
    float ssum = 0.f;
    #pragma unroll
    for (int z = 0; z < 32; ++z) {
        float* slot = (p < 2) ? &sH[w][p*32+z] : &sW[w][(p-2)*32+z];
        float e = __expf(*slot - M);
        ssum += e;
        *slot = e;
    }
    red[4+p][w] = ssum;
    __syncthreads();
    float S = red[4][w] + red[5][w] + red[6][w] + red[7][w];
    float rinv = 1.f / S;
    const size_t obase = (size_t)(b*NO + hb)*NHW;
    #pragma unroll
    for (int z = 0; z < 32; ++z) {
        if (p < 2) {
            int i = p*32 + z;
            aH2[obase + i*NW + w] = sH[w][i] * rinv;
        } else {
            int j = (p-2)*32 + z;
            aW2[obase + j*NW + w] = sW[w][j] * rinv;
        }
    }
}

// K3: column pass, block per (b, w): out[c][h] = sum_i v[b][c][i][w] * aH[b,h,w,i]
__global__ __launch_bounds__(256) void col_pass(
    const __hip_bfloat16* __restrict__ v, const float* __restrict__ aH2,
    float* __restrict__ out)
{
    __shared__ float vcs[512*68];  // [c][i] stride 68
    __shared__ float AlT[64*68];   // [i][h] stride 68
    const int t = threadIdx.x;
    const int w = blockIdx.x, b = blockIdx.y;
    #pragma unroll 2
    for (int s = 0; s < 16; ++s) {
        int idx = t + 256*s;
        int h = idx >> 6, i = idx & 63;
        AlT[i*68 + h] = aH2[(size_t)(b*NO + h)*NHW + i*NW + w];
    }
    #pragma unroll 4
    for (int s = 0; s < 128; ++s) {
        int idx = t + 256*s;
        int c = idx >> 6, i = idx & 63;
        vcs[c*68 + i] = __bfloat162float(v[(size_t)(b*NC + c)*NHW + i*NW + w]);
    }
    __syncthreads();
    const int h4 = t & 15, cg = t >> 4;
    for (int cb = 0; cb < 8; ++cb) {
        const int c = (cb*16 + cg)*4;
        float acc[4][4] = {};
        #pragma unroll
        for (int i0 = 0; i0 < 64; i0 += 4) {
            float aa[4][4], vv[4][4];
            #pragma unroll
            for (int di = 0; di < 4; ++di)
                *(float4*)aa[di] = *(const float4*)&AlT[(i0+di)*68 + h4*4];
            #pragma unroll
            for (int r = 0; r < 4; ++r)
                *(float4*)vv[r] = *(const float4*)&vcs[(c+r)*68 + i0];
            #pragma unroll
            for (int r = 0; r < 4; ++r)
                #pragma unroll
                for (int di = 0; di < 4; ++di)
                    #pragma unroll
                    for (int hh = 0; hh < 4; ++hh)
                        acc[r][hh] += vv[r][di] * aa[di][hh];
        }
        #pragma unroll
        for (int r = 0; r < 4; ++r)
            #pragma unroll
            for (int hh = 0; hh < 4; ++hh)
                out[(size_t)((b*NC + c + r)*NH + h4*4 + hh)*NW + w] = acc[r][hh];
    }
}

// K4: row pass + residual, block per (b, h):
//   out = gamma*(colsum + sum_j v[b][c][h][j]*aW[b,h,w,j]) + x
__global__ __launch_bounds__(256) void row_pass(
    const __hip_bfloat16* __restrict__ v, const float* __restrict__ aW2,
    const float* __restrict__ x, const float* __restrict__ gamma,
    float* __restrict__ out)
{
    __shared__ float vrs[512*68];  // [c][j]
    __shared__ float AwT[64*68];   // [j][w]
    const int t = threadIdx.x;
    const int hb = blockIdx.x, b = blockIdx.y;
    #pragma unroll 2
    for (int s = 0; s < 16; ++s) {
        int idx = t + 256*s;
        int j = idx >> 6, ww = idx & 63;
        AwT[j*68 + ww] = aW2[(size_t)(b*NO + hb)*NHW + j*NW + ww];
    }
    #pragma unroll 4
    for (int s = 0; s < 128; ++s) {
        int idx = t + 256*s;
        int c = idx >> 6, j = idx & 63;
        vrs[c*68 + j] = __bfloat162float(v[(size_t)(b*NC + c)*NHW + hb*NW + j]);
    }
    __syncthreads();
    const float g = gamma[0];
    const int w4 = t & 15, cg = t >> 4;
    for (int cb = 0; cb < 8; ++cb) {
        const int c = (cb*16 + cg)*4;
        float acc[4][4] = {};
        #pragma unroll
        for (int j0 = 0; j0 < 64; j0 += 4) {
            float aa[4][4], vv[4][4];
            #pragma unroll
            for (int dj = 0; dj < 4; ++dj)
                *(float4*)aa[dj] = *(const float4*)&AwT[(j0+dj)*68 + w4*4];
            #pragma unroll
            for (int r = 0; r < 4; ++r)
                *(float4*)vv[r] = *(const float4*)&vrs[(c+r)*68 + j0];
            #pragma unroll
            for (int r = 0; r < 4; ++r)
                #pragma unroll
                for (int dj = 0; dj < 4; ++dj)
                    #pragma unroll
                    for (int ww = 0; ww < 4; ++ww)
                        acc[r][ww] += vv[r][dj] * aa[dj][ww];
        }
        #pragma unroll
        for (int r = 0; r < 4; ++r) {
            size_t base = (size_t)((b*NC + c + r)*NH + hb)*NW + w4*4;
            float4 cv = *(const float4*)&out[base];
            float4 xv = *(const float4*)&x[base];
            float4 res;
            res.x = g*(cv.x + acc[r][0]) + xv.x;
            res.y = g*(cv.y + acc[r][1]) + xv.y;
            res.z = g*(cv.z + acc[r][2]) + xv.z;
            res.w = g*(cv.w + acc[r][3]) + xv.w;
            *(float4*)&out[base] = res;
        }
    }
}

extern "C" void kernel_launch(void* const* d_in, const int* in_sizes, int n_in,
                              void* d_out, int out_size, void* d_ws, size_t ws_size,
                              hipStream_t stream) {
    (void)in_sizes; (void)n_in; (void)out_size; (void)ws_size;
    const float* x     = (const float*)d_in[0];
    const float* Wq    = (const float*)d_in[1];
    const float* bq    = (const float*)d_in[2];
    const float* Wk    = (const float*)d_in[3];
    const float* bk    = (const float*)d_in[4];
    const float* Wv    = (const float*)d_in[5];
    const float* bv    = (const float*)d_in[6];
    const float* gamma = (const float*)d_in[7];
    float* out = (float*)d_out;

    char* wsp = (char*)d_ws;
    __hip_bfloat16* qb  = (__hip_bfloat16*)(wsp);                 //  4,194,304 B
    __hip_bfloat16* kb  = (__hip_bfloat16*)(wsp + 4194304);       //  4,194,304 B
    __hip_bfloat16* vb  = (__hip_bfloat16*)(wsp + 8388608);       // 33,554,432 B
    __hip_bfloat16* Wbf = (__hip_bfloat16*)(wsp + 41943040);      //    655,360 B
    float* bias_all     = (float*)(wsp + 42598400);               //      2,560 B
    // union: xt (dead after qkv_mfma) overlaps aH2+aW2 (written after)
    __hip_bfloat16* xt  = (__hip_bfloat16*)(wsp + 42600960);      // 33,554,432 B
    float* aH2          = (float*)(wsp + 42600960);               //  8,388,608 B
    float* aW2          = (float*)(wsp + 50989568);               //  8,388,608 B
    // total: 76,155,392 B

    pack_w<<<dim3(640), 256, 0, stream>>>(Wq, bq, Wk, bk, Wv, bv, Wbf, bias_all);
    transpose_x<<<dim3(8, 64, NB), 256, 0, stream>>>(x, xt);
    qkv_mfma<<<dim3(32, 5, NB), 256, 0, stream>>>(xt, Wbf, bias_all, qb, kb, vb);
    scores_softmax<<<dim3(NH, NB), 256, 0, stream>>>(qb, kb, aH2, aW2);
    col_pass<<<dim3(NW, NB), 256, 0, stream>>>(vb, aH2, out);
    row_pass<<<dim3(NH, NB), 256, 0, stream>>>(vb, aW2, x, gamma, out);
}

// Round 3
// 141.531 us; speedup vs baseline: 6.0685x; 4.4002x over previous
//
#include <hip/hip_runtime.h>
#include <hip/hip_bf16.h>

#define NB 8
#define NC 512
#define NO 64
#define NH 64
#define NW 64
#define NHW 4096

typedef __attribute__((ext_vector_type(8))) short bf16x8;
typedef __attribute__((ext_vector_type(4))) float f32x4;

__device__ __forceinline__ void gload16(const void* g, void* l) {
    __builtin_amdgcn_global_load_lds(
        (const __attribute__((address_space(1))) void*)g,
        (__attribute__((address_space(3))) void*)l, 16, 0, 0);
}

__device__ __forceinline__ short f2bf_bits(float f) {
    __hip_bfloat16 h = __float2bfloat16(f);
    short s; __builtin_memcpy(&s, &h, 2); return s;
}
__device__ __forceinline__ float bfbits_to_f(short s) {
    unsigned int u = ((unsigned int)(unsigned short)s) << 16;
    float f; __builtin_memcpy(&f, &u, 4); return f;
}

// K0a: pack Wq|Wk|Wv -> Wbf[640][512] bf16, biases -> bias_all[640] f32
__global__ __launch_bounds__(256) void pack_w(
    const float* __restrict__ Wq, const float* __restrict__ bq,
    const float* __restrict__ Wk, const float* __restrict__ bk,
    const float* __restrict__ Wv, const float* __restrict__ bv,
    __hip_bfloat16* __restrict__ Wbf, float* __restrict__ bias_all)
{
    const int row = blockIdx.x;
    const int t = threadIdx.x;
    const float* src; float bias;
    if (row < 64)       { src = Wq + row*NC;        bias = bq[row]; }
    else if (row < 128) { src = Wk + (row-64)*NC;   bias = bk[row-64]; }
    else                { src = Wv + (row-128)*NC;  bias = bv[row-128]; }
    for (int i = t; i < NC; i += 256)
        Wbf[(size_t)row*NC + i] = __float2bfloat16(src[i]);
    if (t == 0) bias_all[row] = bias;
}

// K0b: x[b][c][hw] f32 -> xt[b][hw][c] bf16 (LDS tile transpose)
__global__ __launch_bounds__(256) void transpose_x(
    const float* __restrict__ x, __hip_bfloat16* __restrict__ xt)
{
    __shared__ float tile[64][65];
    const int c0  = blockIdx.x * 64;
    const int hw0 = blockIdx.y * 64;
    const int b   = blockIdx.z;
    const int t = threadIdx.x;
    const int col = t & 63, r4 = t >> 6;
    #pragma unroll
    for (int s = 0; s < 16; ++s) {
        int cr = s*4 + r4;
        tile[cr][col] = x[((size_t)b*NC + c0 + cr)*NHW + hw0 + col];
    }
    __syncthreads();
    #pragma unroll
    for (int s = 0; s < 16; ++s) {
        int wr = s*4 + r4;
        xt[((size_t)b*NHW + hw0 + wr)*NC + c0 + col] = __float2bfloat16(tile[col][wr]);
    }
}

// K1: MFMA QKV projection. Per batch: [640x512] @ [512x4096]^T-staged.
__global__ __launch_bounds__(256) void qkv_mfma(
    const __hip_bfloat16* __restrict__ xt, const __hip_bfloat16* __restrict__ Wbf,
    const float* __restrict__ bias_all,
    __hip_bfloat16* __restrict__ qb, __hip_bfloat16* __restrict__ kb,
    __hip_bfloat16* __restrict__ vb)
{
    __shared__ __align__(16) char As[16384];   // [row 128][k 64] bf16, src-preswizzled
    __shared__ __align__(16) char Bs[16384];   // [col 128][k 64] bf16
    const int t = threadIdx.x;
    const int lane = t & 63;
    const int wv = t >> 6;
    const int wm = wv >> 1, wn = wv & 1;
    const int fr = lane & 15, fg = lane >> 4;
    const int hw0 = blockIdx.x * 128;
    const int o0  = blockIdx.y * 128;
    const int b   = blockIdx.z;
    const __hip_bfloat16* xtb = xt + (size_t)b * NHW * NC;

    f32x4 acc[4][4] = {};

    for (int ks = 0; ks < 8; ++ks) {
        const int k0 = ks * 64;
        #pragma unroll
        for (int s = 0; s < 4; ++s) {
            int linear = s*256 + t;
            int row = linear >> 3, g = linear & 7;
            int gk = (g ^ (row & 7)) * 8;
            gload16(Wbf + (size_t)(o0 + row)*NC + k0 + gk, As + linear*16);
            gload16(xtb + (size_t)(hw0 + row)*NC + k0 + gk, Bs + linear*16);
        }
        __syncthreads();
        #pragma unroll
        for (int kk = 0; kk < 2; ++kk) {
            const int gl = kk*4 + fg;
            bf16x8 af[4], bfr[4];
            #pragma unroll
            for (int mf = 0; mf < 4; ++mf) {
                int r = wm*64 + mf*16 + fr;
                af[mf] = *(const bf16x8*)(As + r*128 + ((gl ^ (r & 7)) << 4));
            }
            #pragma unroll
            for (int nf = 0; nf < 4; ++nf) {
                int c = wn*64 + nf*16 + fr;
                bfr[nf] = *(const bf16x8*)(Bs + c*128 + ((gl ^ (c & 7)) << 4));
            }
            #pragma unroll
            for (int mf = 0; mf < 4; ++mf)
                #pragma unroll
                for (int nf = 0; nf < 4; ++nf)
                    acc[mf][nf] = __builtin_amdgcn_mfma_f32_16x16x32_bf16(
                        af[mf], bfr[nf], acc[mf][nf], 0, 0, 0);
        }
        __syncthreads();
    }

    #pragma unroll
    for (int mf = 0; mf < 4; ++mf) {
        #pragma unroll
        for (int reg = 0; reg < 4; ++reg) {
            int o = o0 + wm*64 + mf*16 + (lane >> 4)*4 + reg;
            float bias = bias_all[o];
            __hip_bfloat16* dst; size_t rowbase;
            if (o < 64)       { dst = qb; rowbase = ((size_t)b*NO + o)*NHW; }
            else if (o < 128) { dst = kb; rowbase = ((size_t)b*NO + (o-64))*NHW; }
            else              { dst = vb; rowbase = ((size_t)b*NC + (o-128))*NHW; }
            #pragma unroll
            for (int nf = 0; nf < 4; ++nf) {
                int hw = hw0 + wn*64 + nf*16 + (lane & 15);
                dst[rowbase + hw] = __float2bfloat16(acc[mf][nf][reg] + bias);
            }
        }
    }
}

// K2: v[b][c][i][w] -> vT[b][c][w][i], XOR-swizzled LDS 64x64 transpose, 1 c per wave
__global__ __launch_bounds__(256) void transpose_v(
    const __hip_bfloat16* __restrict__ v, __hip_bfloat16* __restrict__ vT)
{
    __shared__ __align__(16) short tile[4][64*64];
    const int t = threadIdx.x, wv = t >> 6, lane = t & 63;
    const int c = blockIdx.x*4 + wv, b = blockIdx.y;
    const __hip_bfloat16* src = v + ((size_t)(b*NC + c))*NHW;
    __hip_bfloat16* dst = vT + ((size_t)(b*NC + c))*NHW;
    short* tl = tile[wv];
    #pragma unroll
    for (int s = 0; s < 8; ++s) {
        int i = s*8 + (lane>>3), w0 = (lane&7)*8;
        bf16x8 vv = *(const bf16x8*)(src + i*64 + w0);
        *(bf16x8*)&tl[i*64 + (((w0>>3) ^ ((i>>3)&7)) << 3)] = vv;
    }
    __syncthreads();
    #pragma unroll
    for (int s = 0; s < 8; ++s) {
        int w = s*8 + (lane>>3), i0 = (lane&7)*8;
        bf16x8 ov;
        #pragma unroll
        for (int d = 0; d < 8; ++d)
            ov[d] = tl[(i0+d)*64 + (((w>>3) ^ (lane&7)) << 3) + (w&7)];
        *(bf16x8*)(dst + w*64 + i0) = ov;
    }
}

// K3: scores + softmax, block per (b, h). Emits bf16 attention, k-contiguous:
//   aHb[b][w][h][i], aWb[b][h][w][j]
__global__ __launch_bounds__(256) void scores_softmax(
    const __hip_bfloat16* __restrict__ q, const __hip_bfloat16* __restrict__ k,
    __hip_bfloat16* __restrict__ aHb, __hip_bfloat16* __restrict__ aWb)
{
    __shared__ float qs[64][64];   // [o][w]
    __shared__ float ksr[64][64];  // [o][j]
    __shared__ float sH[64][65];   // [w][i]
    __shared__ float sW[64][65];   // [w][j]
    __shared__ float red[8][64];
    const int t = threadIdx.x;
    const int w = t & 63, p = t >> 6;
    const int hb = blockIdx.x, b = blockIdx.y;
    #pragma unroll
    for (int s = 0; s < 16; ++s) {
        int idx = t + 256*s;
        int o = idx >> 6, ww = idx & 63;
        size_t g = (size_t)(b*NO + o)*NHW + hb*NW + ww;
        qs[o][ww]  = __bfloat162float(q[g]);
        ksr[o][ww] = __bfloat162float(k[g]);
    }
    __syncthreads();
    const int ib = p * 16;
    {
        float acc[16];
        #pragma unroll
        for (int ii = 0; ii < 16; ++ii) acc[ii] = 0.f;
        for (int o = 0; o < 64; ++o) {
            float qv = qs[o][w];
            const __hip_bfloat16* kp = k + (size_t)(b*NO + o)*NHW + ib*NW + w;
            #pragma unroll
            for (int ii = 0; ii < 16; ++ii) acc[ii] += qv * __bfloat162float(kp[ii*NW]);
        }
        #pragma unroll
        for (int ii = 0; ii < 16; ++ii) sH[w][ib+ii] = acc[ii];
    }
    {
        float acc[16];
        #pragma unroll
        for (int jj = 0; jj < 16; ++jj) acc[jj] = 0.f;
        for (int o = 0; o < 64; ++o) {
            float qv = qs[o][w];
            #pragma unroll
            for (int jj = 0; jj < 16; ++jj) acc[jj] += qv * ksr[o][ib+jj];
        }
        #pragma unroll
        for (int jj = 0; jj < 16; ++jj) sW[w][ib+jj] = acc[jj];
    }
    __syncthreads();
    if (t < 64) sH[t][hb] = -1e30f;   // diag mask i == h
    __syncthreads();
    float m = -1e30f;
    #pragma unroll
    for (int z = 0; z < 32; ++z) {
        float val = (p < 2) ? sH[w][p*32+z] : sW[w][(p-2)*32+z];
        m = fmaxf(m, val);
    }
    red[p][w] = m;
    __syncthreads();
    float M = fmaxf(fmaxf(red[0][w], red[1][w]), fmaxf(red[2][w], red[3][w]));
    float ssum = 0.f;
    #pragma unroll
    for (int z = 0; z < 32; ++z) {
        float* slot = (p < 2) ? &sH[w][p*32+z] : &sW[w][(p-2)*32+z];
        float e = __expf(*slot - M);
        ssum += e;
        *slot = e;
    }
    red[4+p][w] = ssum;
    __syncthreads();
    float S = red[4][w] + red[5][w] + red[6][w] + red[7][w];
    float rinv = 1.f / S;
    if (p < 2) {
        size_t base = (((size_t)b*NH + w)*NH + hb)*NO + p*32;
        #pragma unroll
        for (int zz = 0; zz < 4; ++zz) {
            bf16x8 pk;
            #pragma unroll
            for (int d = 0; d < 8; ++d)
                pk[d] = f2bf_bits(sH[w][p*32 + zz*8 + d] * rinv);
            *(bf16x8*)(aHb + base + zz*8) = pk;
        }
    } else {
        size_t base = (((size_t)b*NH + hb)*NH + w)*NO + (p-2)*32;
        #pragma unroll
        for (int zz = 0; zz < 4; ++zz) {
            bf16x8 pk;
            #pragma unroll
            for (int d = 0; d < 8; ++d)
                pk[d] = f2bf_bits(sW[w][(p-2)*32 + zz*8 + d] * rinv);
            *(bf16x8*)(aWb + base + zz*8) = pk;
        }
    }
}

// K4: col pass MFMA. Block (w, chalf, b): C[h][c] = sum_i aH[h][i] * vT[c][i].
// Writes PT[b][w][h][c] bf16.
__global__ __launch_bounds__(256) void col_mfma(
    const __hip_bfloat16* __restrict__ vT, const __hip_bfloat16* __restrict__ aH,
    __hip_bfloat16* __restrict__ PT)
{
    __shared__ __align__(16) char As[64*128];    // aH[w]: [h][i]
    __shared__ __align__(16) char Bs[256*128];   // vT: [c][i]
    const int t = threadIdx.x, lane = t & 63, wn = t >> 6;
    const int fr = lane & 15, fg = lane >> 4;
    const int w = blockIdx.x, chalf = blockIdx.y, b = blockIdx.z;
    const __hip_bfloat16* Ag = aH + ((size_t)(b*NH + w))*4096;
    const __hip_bfloat16* Bg = vT + ((size_t)(b*NC + chalf*256))*NHW + w*64;
    #pragma unroll
    for (int s = 0; s < 2; ++s) {
        int linear = s*256 + t;
        int r = linear >> 3, g = linear & 7;
        gload16(Ag + r*64 + ((g ^ (r&7)) * 8), As + linear*16);
    }
    #pragma unroll
    for (int s = 0; s < 8; ++s) {
        int linear = s*256 + t;
        int r = linear >> 3, g = linear & 7;
        gload16(Bg + (size_t)r*NHW + ((g ^ (r&7)) * 8), Bs + linear*16);
    }
    __syncthreads();
    f32x4 acc[4][4] = {};
    #pragma unroll
    for (int kk = 0; kk < 2; ++kk) {
        int gl = kk*4 + fg;
        bf16x8 af[4], bfv[4];
        #pragma unroll
        for (int mf = 0; mf < 4; ++mf) {
            int r = mf*16 + fr;
            af[mf] = *(const bf16x8*)(As + r*128 + ((gl ^ (r&7)) << 4));
        }
        #pragma unroll
        for (int nf = 0; nf < 4; ++nf) {
            int c = wn*64 + nf*16 + fr;
            bfv[nf] = *(const bf16x8*)(Bs + c*128 + ((gl ^ (c&7)) << 4));
        }
        #pragma unroll
        for (int mf = 0; mf < 4; ++mf)
            #pragma unroll
            for (int nf = 0; nf < 4; ++nf)
                acc[mf][nf] = __builtin_amdgcn_mfma_f32_16x16x32_bf16(
                    af[mf], bfv[nf], acc[mf][nf], 0, 0, 0);
    }
    const size_t base = ((size_t)(b*NH + w))*64*512 + chalf*256;
    #pragma unroll
    for (int mf = 0; mf < 4; ++mf) {
        #pragma unroll
        for (int reg = 0; reg < 4; ++reg) {
            int hh = mf*16 + (lane >> 4)*4 + reg;
            #pragma unroll
            for (int nf = 0; nf < 4; ++nf) {
                int cc = wn*64 + nf*16 + (lane & 15);
                PT[base + (size_t)hh*512 + cc] = __float2bfloat16(acc[mf][nf][reg]);
            }
        }
    }
}

// K5: row pass MFMA + PT add + residual. Block (h, cq, b):
//   C[c][w] = sum_j v[c][j] * aW[w][j];  out = gamma*(C + PT^T) + x
__global__ __launch_bounds__(256) void row_mfma(
    const __hip_bfloat16* __restrict__ vb, const __hip_bfloat16* __restrict__ aW,
    const __hip_bfloat16* __restrict__ PT, const float* __restrict__ x,
    const float* __restrict__ gamma, float* __restrict__ out)
{
    __shared__ __align__(16) char Ws[64*128];   // aW[h]: [w][j]
    __shared__ __align__(16) char Vs[128*128];  // v: [c][j]
    __shared__ __align__(16) short PTs[64*136]; // [w][c], pad 136 (16B-aligned rows)
    const int t = threadIdx.x, lane = t & 63, wm = t >> 6;
    const int fr = lane & 15, fg = lane >> 4;
    const int h = blockIdx.x, cq = blockIdx.y, b = blockIdx.z;
    const int c0 = cq*128;
    const __hip_bfloat16* Ag = aW + ((size_t)(b*NH + h))*4096;
    const __hip_bfloat16* Vg = vb + ((size_t)(b*NC + c0))*NHW + h*64;
    #pragma unroll
    for (int s = 0; s < 2; ++s) {
        int linear = s*256 + t;
        int r = linear >> 3, g = linear & 7;
        gload16(Ag + r*64 + ((g ^ (r&7)) * 8), Ws + linear*16);
    }
    #pragma unroll
    for (int s = 0; s < 4; ++s) {
        int linear = s*256 + t;
        int r = linear >> 3, g = linear & 7;
        gload16(Vg + (size_t)r*NHW + ((g ^ (r&7)) * 8), Vs + linear*16);
    }
    #pragma unroll
    for (int s = 0; s < 4; ++s) {
        int idx = s*256 + t;
        int ww = idx >> 4, cg = idx & 15;
        bf16x8 pv = *(const bf16x8*)(PT + (((size_t)(b*NH + ww))*64 + h)*512 + c0 + cg*8);
        *(bf16x8*)&PTs[ww*136 + cg*8] = pv;
    }
    __syncthreads();
    f32x4 acc[2][4] = {};
    #pragma unroll
    for (int kk = 0; kk < 2; ++kk) {
        int gl = kk*4 + fg;
        bf16x8 vf[2], wf[4];
        #pragma unroll
        for (int mf = 0; mf < 2; ++mf) {
            int c = wm*32 + mf*16 + fr;
            vf[mf] = *(const bf16x8*)(Vs + c*128 + ((gl ^ (c&7)) << 4));
        }
        #pragma unroll
        for (int nf = 0; nf < 4; ++nf) {
            int ww = nf*16 + fr;
            wf[nf] = *(const bf16x8*)(Ws + ww*128 + ((gl ^ (ww&7)) << 4));
        }
        #pragma unroll
        for (int mf = 0; mf < 2; ++mf)
            #pragma unroll
            for (int nf = 0; nf < 4; ++nf)
                acc[mf][nf] = __builtin_amdgcn_mfma_f32_16x16x32_bf16(
                    vf[mf], wf[nf], acc[mf][nf], 0, 0, 0);
    }
    const float g = gamma[0];
    #pragma unroll
    for (int mf = 0; mf < 2; ++mf) {
        #pragma unroll
        for (int reg = 0; reg < 4; ++reg) {
            int cl = wm*32 + mf*16 + (lane >> 4)*4 + reg;
            size_t rowbase = ((size_t)(b*NC + c0 + cl)*NH + h)*NW;
            #pragma unroll
            for (int nf = 0; nf < 4; ++nf) {
                int ww = nf*16 + (lane & 15);
                float ptv = bfbits_to_f(PTs[ww*136 + cl]);
                out[rowbase + ww] = g*(acc[mf][nf][reg] + ptv) + x[rowbase + ww];
            }
        }
    }
}

extern "C" void kernel_launch(void* const* d_in, const int* in_sizes, int n_in,
                              void* d_out, int out_size, void* d_ws, size_t ws_size,
                              hipStream_t stream) {
    (void)in_sizes; (void)n_in; (void)out_size; (void)ws_size;
    const float* x     = (const float*)d_in[0];
    const float* Wq    = (const float*)d_in[1];
    const float* bq    = (const float*)d_in[2];
    const float* Wk    = (const float*)d_in[3];
    const float* bk    = (const float*)d_in[4];
    const float* Wv    = (const float*)d_in[5];
    const float* bv    = (const float*)d_in[6];
    const float* gamma = (const float*)d_in[7];
    float* out = (float*)d_out;

    char* p = (char*)d_ws;
    __hip_bfloat16* Wbf = (__hip_bfloat16*)(p);                //    655,360
    float* bias_all     = (float*)(p + 655360);                //      2,560
    __hip_bfloat16* qb  = (__hip_bfloat16*)(p + 657920);       //  4,194,304
    __hip_bfloat16* kb  = (__hip_bfloat16*)(p + 4852224);      //  4,194,304
    __hip_bfloat16* vb  = (__hip_bfloat16*)(p + 9046528);      // 33,554,432
    __hip_bfloat16* xt  = (__hip_bfloat16*)(p + 42600960);     // 33,554,432 (dead after qkv)
    __hip_bfloat16* vT  = (__hip_bfloat16*)(p + 42600960);     //   aliases xt
    __hip_bfloat16* aHb = (__hip_bfloat16*)(p + 76155392);     //  4,194,304
    __hip_bfloat16* aWb = (__hip_bfloat16*)(p + 80349696);     //  4,194,304
    __hip_bfloat16* PT  = (__hip_bfloat16*)(p + 84544000);     // 33,554,432
    // total 118,098,432 B

    pack_w<<<dim3(640), 256, 0, stream>>>(Wq, bq, Wk, bk, Wv, bv, Wbf, bias_all);
    transpose_x<<<dim3(8, 64, NB), 256, 0, stream>>>(x, xt);
    qkv_mfma<<<dim3(32, 5, NB), 256, 0, stream>>>(xt, Wbf, bias_all, qb, kb, vb);
    transpose_v<<<dim3(128, NB), 256, 0, stream>>>(vb, vT);
    scores_softmax<<<dim3(NH, NB), 256, 0, stream>>>(qb, kb, aHb, aWb);
    col_mfma<<<dim3(NW, 2, NB), 256, 0, stream>>>(vT, aHb, PT);
    row_mfma<<<dim3(NH, 4, NB), 256, 0, stream>>>(vb, aWb, PT, x, gamma, out);
}